// Round 13
// baseline (324.091 us; speedup 1.0000x reference)
//
#include <hip/hip_runtime.h>

constexpr int C = 768;
constexpr int NPATCH = 1024;   // (448/14)^2
constexpr int H = 448, W = 448;
constexpr int HW = H * W;      // 200704
constexpr int TOPK = 200;      // int(200704 * 0.001)
constexpr float EPS = 1e-12f;

constexpr int HBITS = 13;
constexpr int HBINS = 1 << HBITS;   // 8192
constexpr int HSHIFT = 18;          // bin = float_bits >> 18 (sign always 0)
constexpr int CSTRIDE = 64;         // ints between per-batch counters (256B)
constexpr int CBLK = HW / 1024;     // compact blocks per batch = 196

typedef float f32x4 __attribute__((ext_vector_type(4)));

__device__ __forceinline__ float dotv(const f32x4 a, const f32x4 b) {
    return a.x * b.x + a.y * b.y + a.z * b.z + a.w * b.w;
}

// One wave per (b,n) row, nontemporal loads. First 132 blocks also zero the
// 528KB meta+hist scratch (4KB each) — replaces a separate zero kernel.
__global__ __launch_bounds__(256, 4) void anom_kernel(
    const float* __restrict__ m, const float* __restrict__ l,
    const float* __restrict__ pm, const float* __restrict__ pl,
    float* __restrict__ combined, uint4* __restrict__ zp, int n4, int rows) {
    if (blockIdx.x < 132) {
        int z = blockIdx.x * 256 + threadIdx.x;
        if (z < n4) zp[z] = make_uint4(0u, 0u, 0u, 0u);
    }
    int wid = (int)((blockIdx.x * blockDim.x + threadIdx.x) >> 6);
    int lane = threadIdx.x & 63;
    if (wid >= rows) return;
    size_t base = (size_t)wid * C;
    const f32x4* A = (const f32x4*)(m + base);
    const f32x4* B = (const f32x4*)(pm + base);
    const f32x4* Cc = (const f32x4*)(l + base);
    const f32x4* D = (const f32x4*)(pl + base);

    f32x4 a0 = __builtin_nontemporal_load(A + lane);
    f32x4 a1 = __builtin_nontemporal_load(A + lane + 64);
    f32x4 a2 = __builtin_nontemporal_load(A + lane + 128);
    f32x4 b0 = __builtin_nontemporal_load(B + lane);
    f32x4 b1 = __builtin_nontemporal_load(B + lane + 64);
    f32x4 b2 = __builtin_nontemporal_load(B + lane + 128);
    f32x4 c0 = __builtin_nontemporal_load(Cc + lane);
    f32x4 c1 = __builtin_nontemporal_load(Cc + lane + 64);
    f32x4 c2 = __builtin_nontemporal_load(Cc + lane + 128);
    f32x4 d0 = __builtin_nontemporal_load(D + lane);
    f32x4 d1 = __builtin_nontemporal_load(D + lane + 64);
    f32x4 d2 = __builtin_nontemporal_load(D + lane + 128);

    float mm = dotv(a0, a0) + dotv(a1, a1) + dotv(a2, a2);
    float pp = dotv(b0, b0) + dotv(b1, b1) + dotv(b2, b2);
    float mp = dotv(a0, b0) + dotv(a1, b1) + dotv(a2, b2);
    float ll = dotv(c0, c0) + dotv(c1, c1) + dotv(c2, c2);
    float qq = dotv(d0, d0) + dotv(d1, d1) + dotv(d2, d2);
    float lq = dotv(c0, d0) + dotv(c1, d1) + dotv(c2, d2);

#pragma unroll
    for (int off = 32; off > 0; off >>= 1) {
        mm += __shfl_xor(mm, off);
        pp += __shfl_xor(pp, off);
        mp += __shfl_xor(mp, off);
        ll += __shfl_xor(ll, off);
        qq += __shfl_xor(qq, off);
        lq += __shfl_xor(lq, off);
    }
    if (lane == 0) {
        float rm = 1.0f / fmaxf(sqrtf(mm), EPS);
        float rp = 1.0f / fmaxf(sqrtf(pp), EPS);
        float rl = 1.0f / fmaxf(sqrtf(ll), EPS);
        float rq = 1.0f / fmaxf(sqrtf(qq), EPS);
        float d2m = fmaxf(mm * rm * rm - 2.f * mp * rm * rp + pp * rp * rp, 0.f);
        float d2l = fmaxf(ll * rl * rl - 2.f * lq * rl * rq + qq * rq * rq, 0.f);
        combined[wid] = sqrtf(d2m) * sqrtf(d2l);
    }
}

// ---- upsample+blur as map = G * comb * G^T (exact linear factorization) ----
// G (448x32) = 8-pass 1D zero-pad box-blur chain applied to the clamped
// half-pixel bilinear basis. Each stageA block rebuilds G in LDS (parallel,
// identical); block 0 stores it to global for stageB.

// Builds g[i][x] = G[x][i] in LDS. 448 threads = 32 cols x 14 chunks of 32 x.
__device__ void build_G(float (*g)[449], int tid) {
    int i = tid & 31;       // grid column
    int chunk = tid >> 5;   // 0..13
    int x0 = chunk * 32;

#pragma unroll 1
    for (int k = 0; k < 32; ++k) {
        int x = x0 + k;
        float sx = (x + 0.5f) * (1.0f / 14.0f) - 0.5f;
        float f0 = floorf(sx);
        float fx = sx - f0;
        int q0 = (int)f0;
        int q0c = min(max(q0, 0), 31);
        int q1c = min(max(q0 + 1, 0), 31);
        float w = 0.f;
        if (q0c == i) w += 1.0f - fx;
        if (q1c == i) w += fx;
        g[i][x] = w;
    }
    __syncthreads();

#pragma unroll 1
    for (int pass = 0; pass < 8; ++pass) {
        float win[38];
#pragma unroll
        for (int j = 0; j < 38; ++j) {
            int xw = x0 - 3 + j;
            win[j] = (xw >= 0 && xw < 448) ? g[i][xw] : 0.f;
        }
        float out[32];
        if (pass < 5) {
            constexpr float inv5 = 1.0f / 5.0f;
#pragma unroll
            for (int k = 0; k < 32; ++k)
                out[k] = (win[k + 1] + win[k + 2] + win[k + 3] + win[k + 4] +
                          win[k + 5]) * inv5;
        } else {
            constexpr float inv7 = 1.0f / 7.0f;
#pragma unroll
            for (int k = 0; k < 32; ++k)
                out[k] = (win[k] + win[k + 1] + win[k + 2] + win[k + 3] +
                          win[k + 4] + win[k + 5] + win[k + 6]) * inv7;
        }
        __syncthreads();
#pragma unroll
        for (int k = 0; k < 32; ++k) g[i][x0 + k] = out[k];
        __syncthreads();
    }
}

// T[b][x][i] = sum_j G[x][j]*comb[b][i][j]; block 0 also exports G.
__global__ __launch_bounds__(448) void stageA_kernel(
    const float* __restrict__ comb, float* __restrict__ Gout,
    float* __restrict__ T) {
    __shared__ float g[32][449];     // g[i][x] = G[x][i]
    __shared__ float combT[32][32];  // [j][i]
    int b = blockIdx.x;
    int x = threadIdx.x;
    const float* cb = comb + (size_t)b * 1024;
    for (int idx = x; idx < 1024; idx += 448)
        combT[idx & 31][idx >> 5] = cb[idx];

    build_G(g, x);  // barriers inside cover combT too

    f32x4 acc[8];
#pragma unroll
    for (int k = 0; k < 8; ++k) acc[k] = (f32x4){0.f, 0.f, 0.f, 0.f};
#pragma unroll 1
    for (int j = 0; j < 32; ++j) {
        float w = g[j][x];  // G[x][j]; consecutive x -> conflict-free
#pragma unroll
        for (int k = 0; k < 8; ++k) {
            f32x4 c = *(const f32x4*)&combT[j][k * 4];
            acc[k] += c * w;
        }
    }
    float* t = T + ((size_t)b * 448 + x) * 32;
#pragma unroll
    for (int k = 0; k < 8; ++k) *(f32x4*)(t + k * 4) = acc[k];

    if (b == 0) {
        for (int idx = x; idx < 448 * 32; idx += 448)
            Gout[idx] = g[idx & 31][idx >> 5];  // Gout[y*32+i] = G[y][i]
    }
}

// map = G*T fused with per-batch histogram; the LAST block of each batch
// (16 per batch) additionally runs the suffix-scan bin select.
__global__ __launch_bounds__(448) void stageB_kernel(
    const float* __restrict__ T, const float* __restrict__ G,
    float* __restrict__ map, unsigned* __restrict__ hist,
    int* __restrict__ done, int* __restrict__ selbin) {
    __shared__ float gband[28][32];
    __shared__ unsigned lh[HBINS];
    __shared__ int is_last;
    int b = blockIdx.x >> 4;
    int band = blockIdx.x & 15;
    int x = threadIdx.x;

    for (int i = x; i < HBINS; i += 448) lh[i] = 0;
    for (int i = x; i < 28 * 32; i += 448)
        gband[i >> 5][i & 31] = G[(band * 28 + (i >> 5)) * 32 + (i & 31)];
    f32x4 t[8];
    const float* tp = T + ((size_t)b * 448 + x) * 32;
#pragma unroll
    for (int k = 0; k < 8; ++k) t[k] = *(const f32x4*)(tp + k * 4);
    __syncthreads();

    float* out = map + (size_t)b * HW + (size_t)band * 28 * W;
#pragma unroll 1
    for (int yy = 0; yy < 28; ++yy) {
        f32x4 a = {0.f, 0.f, 0.f, 0.f};
#pragma unroll
        for (int k = 0; k < 8; ++k) {
            f32x4 g4 = *(const f32x4*)&gband[yy][k * 4];
            a += g4 * t[k];
        }
        float v = a.x + a.y + a.z + a.w;
        out[yy * W + x] = v;
        atomicAdd(&lh[__float_as_uint(v) >> HSHIFT], 1u);
    }
    __syncthreads();
    unsigned* gh = hist + (size_t)b * HBINS;
    for (int i = x; i < HBINS; i += 448) {
        unsigned c = lh[i];
        if (c) atomicAdd(&gh[i], c);
    }

    // arrival: last block of this batch runs the select
    __threadfence();
    __syncthreads();
    if (x == 0) is_last = (atomicAdd(&done[b * CSTRIDE], 1) == 15);
    __syncthreads();
    if (!is_last) return;
    __threadfence();

    __shared__ unsigned ss[257];
    __shared__ unsigned cs2[33];
    __shared__ int sh_base, sh_k;
    if (x < 256) {
        unsigned s = 0;
#pragma unroll
        for (int j = 0; j < 32; ++j) s += gh[x * 32 + j];
        ss[x] = s;
        if (x == 0) ss[256] = 0;
    }
    __syncthreads();
#pragma unroll
    for (int st = 1; st < 256; st <<= 1) {
        unsigned add = (x < 256 && x + st < 256) ? ss[x + st] : 0u;
        __syncthreads();
        if (x < 256) ss[x] += add;
        __syncthreads();
    }
    if (x < 256 && (int)ss[x] >= TOPK && (int)ss[x + 1] < TOPK) {
        sh_base = x * 32;
        sh_k = TOPK - (int)ss[x + 1];
    }
    __syncthreads();
    int base = sh_base, kk = sh_k;
    if (x < 32) cs2[x] = gh[base + x];
    if (x == 0) cs2[32] = 0;
    __syncthreads();
#pragma unroll
    for (int st = 1; st < 32; st <<= 1) {
        unsigned add = (x < 32 && x + st < 32) ? cs2[x + st] : 0u;
        __syncthreads();
        if (x < 32) cs2[x] += add;
        __syncthreads();
    }
    if (x < 32 && (int)cs2[x] >= kk && (int)cs2[x + 1] < kk)
        selbin[b * CSTRIDE] = base + x;
}

// Candidate compaction; the LAST block of each batch (196) runs the exact
// radix-select top-200 mean over the compacted candidates.
__global__ __launch_bounds__(256) void compact_topk_kernel(
    const float* __restrict__ map, const int* __restrict__ selbin,
    int* __restrict__ ccount, int* __restrict__ done2,
    float* __restrict__ cand, float* __restrict__ score) {
    int tid = threadIdx.x;
    size_t base = (size_t)blockIdx.x * 1024;
    int b = (int)(base / HW);
    int sb = selbin[b * CSTRIDE];
    const uint4* u4 = (const uint4*)(((const unsigned*)map) + base);
    uint4 v = u4[tid];
    unsigned take0 = ((int)(v.x >> HSHIFT) >= sb);
    unsigned take1 = ((int)(v.y >> HSHIFT) >= sb);
    unsigned take2 = ((int)(v.z >> HSHIFT) >= sb);
    unsigned take3 = ((int)(v.w >> HSHIFT) >= sb);
    int c = (int)(take0 + take1 + take2 + take3);

    __shared__ int blkcnt, blkbase, is_last;
    if (tid == 0) blkcnt = 0;
    __syncthreads();
    int pos = 0;
    if (c) pos = atomicAdd(&blkcnt, c);
    __syncthreads();
    if (tid == 0 && blkcnt > 0)
        blkbase = atomicAdd(&ccount[b * CSTRIDE], blkcnt);
    __syncthreads();
    if (c) {
        float* o = cand + (size_t)b * HW + blkbase + pos;
        if (take0) *o++ = __uint_as_float(v.x);
        if (take1) *o++ = __uint_as_float(v.y);
        if (take2) *o++ = __uint_as_float(v.z);
        if (take3) *o = __uint_as_float(v.w);
    }

    __threadfence();
    __syncthreads();
    if (tid == 0) is_last = (atomicAdd(&done2[b * CSTRIDE], 1) == CBLK - 1);
    __syncthreads();
    if (!is_last) return;
    __threadfence();

    // ---- exact top-200 mean over candidates ----
    const float* s = cand + (size_t)b * HW;
    const unsigned* u = (const unsigned*)s;
    int M = ccount[b * CSTRIDE];
    __shared__ unsigned hist[256];
    __shared__ unsigned ss[257];
    __shared__ unsigned sh_prefix;
    __shared__ int sh_k;

    unsigned prefix = 0;
    int k = TOPK;
    for (int dgt = 3; dgt >= 0; --dgt) {
        hist[tid] = 0;
        __syncthreads();
        for (int i = tid; i < M; i += 256) {
            unsigned vv = u[i];
            bool match = (dgt == 3) || ((vv >> (8 * (dgt + 1))) == prefix);
            if (match) atomicAdd(&hist[(vv >> (8 * dgt)) & 255u], 1u);
        }
        __syncthreads();
        ss[tid] = hist[tid];
        if (tid == 0) ss[256] = 0;
        __syncthreads();
#pragma unroll
        for (int st = 1; st < 256; st <<= 1) {
            unsigned add = (tid + st < 256) ? ss[tid + st] : 0u;
            __syncthreads();
            ss[tid] += add;
            __syncthreads();
        }
        if ((int)ss[tid] >= k && (int)ss[tid + 1] < k) {
            sh_prefix = (prefix << 8) | (unsigned)tid;
            sh_k = k - (int)ss[tid + 1];
        }
        __syncthreads();
        prefix = sh_prefix;
        k = sh_k;
        __syncthreads();
    }

    float thr = __uint_as_float(prefix);
    float sum = 0.f;
    int cnt = 0;
    for (int i = tid; i < M; i += 256) {
        float vv = s[i];
        if (vv > thr) { sum += vv; cnt++; }
    }
#pragma unroll
    for (int off = 32; off > 0; off >>= 1) {
        sum += __shfl_xor(sum, off);
        cnt += __shfl_xor(cnt, off);
    }
    __shared__ float wsum[4];
    __shared__ int wcnt[4];
    int wv = tid >> 6;
    if ((tid & 63) == 0) { wsum[wv] = sum; wcnt[wv] = cnt; }
    __syncthreads();
    if (tid == 0) {
        float s2 = 0.f;
        int c2 = 0;
        for (int i = 0; i < 4; ++i) { s2 += wsum[i]; c2 += wcnt[i]; }
        score[b] = (s2 + (float)(TOPK - c2) * thr) * (1.0f / TOPK);
    }
}

extern "C" void kernel_launch(void* const* d_in, const int* in_sizes, int n_in,
                              void* d_out, int out_size, void* d_ws, size_t ws_size,
                              hipStream_t stream) {
    const float* mid = (const float*)d_in[0];
    const float* last = (const float*)d_in[1];
    const float* pmid = (const float*)d_in[2];
    const float* plast = (const float*)d_in[3];
    int B = in_sizes[0] / (NPATCH * C);  // 16

    float* out_map = (float*)d_out;                   // B*448*448
    float* out_score = out_map + (size_t)B * HW;      // B

    // ws layout
    float* combined = (float*)d_ws;                          // 0..64K
    int* meta = (int*)((char*)d_ws + 64 * 1024);             // 64K..80K
    int* ccount = meta;                                      // [b*CSTRIDE]
    int* selbin = meta + 1024;                               // +4KB
    int* done = meta + 2048;                                 // +8KB
    int* done2 = meta + 3072;                                // +12KB
    unsigned* hist = (unsigned*)((char*)d_ws + 80 * 1024);   // 80K..592K
    float* Gw = (float*)((char*)d_ws + 592 * 1024);          // 57,344B
    float* Tw = (float*)((char*)d_ws + 652 * 1024);          // 896KB
    float* cand = (float*)((char*)d_ws + 1548 * 1024);       // B*HW floats

    int rows = B * NPATCH;
    int n4 = (528 * 1024) / 16;  // meta (16KB) + hist (512KB)
    anom_kernel<<<(rows + 3) / 4, 256, 0, stream>>>(
        mid, last, pmid, plast, combined,
        (uint4*)((char*)d_ws + 64 * 1024), n4, rows);

    stageA_kernel<<<B, 448, 0, stream>>>(combined, Gw, Tw);
    stageB_kernel<<<B * 16, 448, 0, stream>>>(Tw, Gw, out_map, hist, done,
                                              selbin);
    compact_topk_kernel<<<B * CBLK, 256, 0, stream>>>(out_map, selbin, ccount,
                                                      done2, cand, out_score);
}

// Round 14
// 100.332 us; speedup vs baseline: 3.2302x; 3.2302x over previous
//
#include <hip/hip_runtime.h>

constexpr int C = 768;
constexpr int NPATCH = 1024;   // (448/14)^2
constexpr int H = 448, W = 448;
constexpr int HW = H * W;      // 200704
constexpr int TOPK = 200;      // int(200704 * 0.001)
constexpr float EPS = 1e-12f;

constexpr int HBITS = 13;
constexpr int HBINS = 1 << HBITS;   // 8192
constexpr int HSHIFT = 18;          // bin = float_bits >> 18 (sign always 0)
constexpr int CSTRIDE = 64;         // ints between per-batch counters (256B)

typedef float f32x4 __attribute__((ext_vector_type(4)));

__device__ __forceinline__ float dotv(const f32x4 a, const f32x4 b) {
    return a.x * b.x + a.y * b.y + a.z * b.z + a.w * b.w;
}

// One wave per (b,n) row, nontemporal loads. First 132 blocks also zero the
// 528KB meta+hist scratch (sync-free fusion; consumers are later kernels).
__global__ __launch_bounds__(256, 4) void anom_kernel(
    const float* __restrict__ m, const float* __restrict__ l,
    const float* __restrict__ pm, const float* __restrict__ pl,
    float* __restrict__ combined, uint4* __restrict__ zp, int n4, int rows) {
    if (blockIdx.x < 132) {
        int z = blockIdx.x * 256 + threadIdx.x;
        if (z < n4) zp[z] = make_uint4(0u, 0u, 0u, 0u);
    }
    int wid = (int)((blockIdx.x * blockDim.x + threadIdx.x) >> 6);
    int lane = threadIdx.x & 63;
    if (wid >= rows) return;
    size_t base = (size_t)wid * C;
    const f32x4* A = (const f32x4*)(m + base);
    const f32x4* B = (const f32x4*)(pm + base);
    const f32x4* Cc = (const f32x4*)(l + base);
    const f32x4* D = (const f32x4*)(pl + base);

    f32x4 a0 = __builtin_nontemporal_load(A + lane);
    f32x4 a1 = __builtin_nontemporal_load(A + lane + 64);
    f32x4 a2 = __builtin_nontemporal_load(A + lane + 128);
    f32x4 b0 = __builtin_nontemporal_load(B + lane);
    f32x4 b1 = __builtin_nontemporal_load(B + lane + 64);
    f32x4 b2 = __builtin_nontemporal_load(B + lane + 128);
    f32x4 c0 = __builtin_nontemporal_load(Cc + lane);
    f32x4 c1 = __builtin_nontemporal_load(Cc + lane + 64);
    f32x4 c2 = __builtin_nontemporal_load(Cc + lane + 128);
    f32x4 d0 = __builtin_nontemporal_load(D + lane);
    f32x4 d1 = __builtin_nontemporal_load(D + lane + 64);
    f32x4 d2 = __builtin_nontemporal_load(D + lane + 128);

    float mm = dotv(a0, a0) + dotv(a1, a1) + dotv(a2, a2);
    float pp = dotv(b0, b0) + dotv(b1, b1) + dotv(b2, b2);
    float mp = dotv(a0, b0) + dotv(a1, b1) + dotv(a2, b2);
    float ll = dotv(c0, c0) + dotv(c1, c1) + dotv(c2, c2);
    float qq = dotv(d0, d0) + dotv(d1, d1) + dotv(d2, d2);
    float lq = dotv(c0, d0) + dotv(c1, d1) + dotv(c2, d2);

#pragma unroll
    for (int off = 32; off > 0; off >>= 1) {
        mm += __shfl_xor(mm, off);
        pp += __shfl_xor(pp, off);
        mp += __shfl_xor(mp, off);
        ll += __shfl_xor(ll, off);
        qq += __shfl_xor(qq, off);
        lq += __shfl_xor(lq, off);
    }
    if (lane == 0) {
        float rm = 1.0f / fmaxf(sqrtf(mm), EPS);
        float rp = 1.0f / fmaxf(sqrtf(pp), EPS);
        float rl = 1.0f / fmaxf(sqrtf(ll), EPS);
        float rq = 1.0f / fmaxf(sqrtf(qq), EPS);
        float d2m = fmaxf(mm * rm * rm - 2.f * mp * rm * rp + pp * rp * rp, 0.f);
        float d2l = fmaxf(ll * rl * rl - 2.f * lq * rl * rq + qq * rq * rq, 0.f);
        combined[wid] = sqrtf(d2m) * sqrtf(d2l);
    }
}

// ---- upsample+blur as map = G * comb * G^T (exact linear factorization) ----
// G (448x32) = 8-pass 1D zero-pad box-blur chain applied to the clamped
// half-pixel bilinear basis. Each stageA block rebuilds G in LDS (parallel,
// redundant, sync-free); block 0 exports it for stageB.

// Builds g[i][x] = G[x][i] in LDS. 448 threads = 32 cols x 14 chunks of 32 x.
__device__ void build_G(float (*g)[449], int tid) {
    int i = tid & 31;       // grid column
    int chunk = tid >> 5;   // 0..13
    int x0 = chunk * 32;

#pragma unroll 1
    for (int k = 0; k < 32; ++k) {
        int x = x0 + k;
        float sx = (x + 0.5f) * (1.0f / 14.0f) - 0.5f;
        float f0 = floorf(sx);
        float fx = sx - f0;
        int q0 = (int)f0;
        int q0c = min(max(q0, 0), 31);
        int q1c = min(max(q0 + 1, 0), 31);
        float w = 0.f;
        if (q0c == i) w += 1.0f - fx;
        if (q1c == i) w += fx;
        g[i][x] = w;
    }
    __syncthreads();

#pragma unroll 1
    for (int pass = 0; pass < 8; ++pass) {
        float win[38];
#pragma unroll
        for (int j = 0; j < 38; ++j) {
            int xw = x0 - 3 + j;
            win[j] = (xw >= 0 && xw < 448) ? g[i][xw] : 0.f;
        }
        float out[32];
        if (pass < 5) {
            constexpr float inv5 = 1.0f / 5.0f;
#pragma unroll
            for (int k = 0; k < 32; ++k)
                out[k] = (win[k + 1] + win[k + 2] + win[k + 3] + win[k + 4] +
                          win[k + 5]) * inv5;
        } else {
            constexpr float inv7 = 1.0f / 7.0f;
#pragma unroll
            for (int k = 0; k < 32; ++k)
                out[k] = (win[k] + win[k + 1] + win[k + 2] + win[k + 3] +
                          win[k + 4] + win[k + 5] + win[k + 6]) * inv7;
        }
        __syncthreads();
#pragma unroll
        for (int k = 0; k < 32; ++k) g[i][x0 + k] = out[k];
        __syncthreads();
    }
}

// T[b][x][i] = sum_j G[x][j]*comb[b][i][j]; block 0 also exports G.
__global__ __launch_bounds__(448) void stageA_kernel(
    const float* __restrict__ comb, float* __restrict__ Gout,
    float* __restrict__ T) {
    __shared__ float g[32][449];     // g[i][x] = G[x][i]
    __shared__ float combT[32][32];  // [j][i]
    int b = blockIdx.x;
    int x = threadIdx.x;
    const float* cb = comb + (size_t)b * 1024;
    for (int idx = x; idx < 1024; idx += 448)
        combT[idx & 31][idx >> 5] = cb[idx];

    build_G(g, x);  // internal barriers cover combT too

    f32x4 acc[8];
#pragma unroll
    for (int k = 0; k < 8; ++k) acc[k] = (f32x4){0.f, 0.f, 0.f, 0.f};
#pragma unroll 1
    for (int j = 0; j < 32; ++j) {
        float w = g[j][x];  // G[x][j]; consecutive x -> conflict-free
#pragma unroll
        for (int k = 0; k < 8; ++k) {
            f32x4 c = *(const f32x4*)&combT[j][k * 4];
            acc[k] += c * w;
        }
    }
    float* t = T + ((size_t)b * 448 + x) * 32;
#pragma unroll
    for (int k = 0; k < 8; ++k) *(f32x4*)(t + k * 4) = acc[k];

    if (b == 0) {
        for (int idx = x; idx < 448 * 32; idx += 448)
            Gout[idx] = g[idx & 31][idx >> 5];  // Gout[y*32+i] = G[y][i]
    }
}

// map = G*T fused with per-batch histogram (values live in registers here).
// 256 blocks = 16 b x 16 bands. No cross-block sync (select is own kernel).
__global__ __launch_bounds__(448) void stageB_kernel(
    const float* __restrict__ T, const float* __restrict__ G,
    float* __restrict__ map, unsigned* __restrict__ hist) {
    __shared__ float gband[28][32];
    __shared__ unsigned lh[HBINS];
    int b = blockIdx.x >> 4;
    int band = blockIdx.x & 15;
    int x = threadIdx.x;

    for (int i = x; i < HBINS; i += 448) lh[i] = 0;
    for (int i = x; i < 28 * 32; i += 448)
        gband[i >> 5][i & 31] = G[(band * 28 + (i >> 5)) * 32 + (i & 31)];
    f32x4 t[8];
    const float* tp = T + ((size_t)b * 448 + x) * 32;
#pragma unroll
    for (int k = 0; k < 8; ++k) t[k] = *(const f32x4*)(tp + k * 4);
    __syncthreads();

    float* out = map + (size_t)b * HW + (size_t)band * 28 * W;
#pragma unroll 1
    for (int yy = 0; yy < 28; ++yy) {
        f32x4 a = {0.f, 0.f, 0.f, 0.f};
#pragma unroll
        for (int k = 0; k < 8; ++k) {
            f32x4 g4 = *(const f32x4*)&gband[yy][k * 4];
            a += g4 * t[k];
        }
        float v = a.x + a.y + a.z + a.w;
        out[yy * W + x] = v;
        atomicAdd(&lh[__float_as_uint(v) >> HSHIFT], 1u);
    }
    __syncthreads();
    unsigned* gh = hist + (size_t)b * HBINS;
    for (int i = x; i < HBINS; i += 448) {
        unsigned c = lh[i];
        if (c) atomicAdd(&gh[i], c);
    }
}

// ---------------- grid-parallel exact top-k ----------------

// Parallel suffix-scan select: largest bin with count(bins >= bin) >= TOPK.
__global__ __launch_bounds__(256) void select_kernel(
    const unsigned* __restrict__ hist, int* __restrict__ selbin) {
    int b = blockIdx.x;
    const unsigned* gh = hist + (size_t)b * HBINS;
    constexpr int CHUNK = HBINS / 256;  // 32
    __shared__ unsigned ss[257];
    __shared__ unsigned cs2[33];
    __shared__ int sh_base, sh_k;
    int tid = threadIdx.x;
    unsigned s = 0;
#pragma unroll
    for (int j = 0; j < CHUNK; ++j) s += gh[tid * CHUNK + j];
    ss[tid] = s;
    if (tid == 0) ss[256] = 0;
    __syncthreads();
#pragma unroll
    for (int st = 1; st < 256; st <<= 1) {
        unsigned add = (tid + st < 256) ? ss[tid + st] : 0u;
        __syncthreads();
        ss[tid] += add;
        __syncthreads();
    }
    if ((int)ss[tid] >= TOPK && (int)ss[tid + 1] < TOPK) {
        sh_base = tid * CHUNK;
        sh_k = TOPK - (int)ss[tid + 1];
    }
    __syncthreads();
    int base = sh_base, kk = sh_k;
    if (tid < 32) cs2[tid] = gh[base + tid];
    if (tid == 0) cs2[32] = 0;
    __syncthreads();
#pragma unroll
    for (int st = 1; st < 32; st <<= 1) {
        unsigned add = (tid < 32 && tid + st < 32) ? cs2[tid + st] : 0u;
        __syncthreads();
        if (tid < 32) cs2[tid] += add;
        __syncthreads();
    }
    if (tid < 32 && (int)cs2[tid] >= kk && (int)cs2[tid + 1] < kk)
        selbin[b * CSTRIDE] = base + tid;
}

__global__ __launch_bounds__(256) void compact_kernel(
    const float* __restrict__ map, const int* __restrict__ selbin,
    int* __restrict__ ccount, float* __restrict__ cand) {
    int tid = threadIdx.x;
    size_t base = (size_t)blockIdx.x * 1024;
    int b = (int)(base / HW);
    int sb = selbin[b * CSTRIDE];
    const uint4* u4 = (const uint4*)(((const unsigned*)map) + base);
    uint4 v = u4[tid];
    unsigned take0 = ((int)(v.x >> HSHIFT) >= sb);
    unsigned take1 = ((int)(v.y >> HSHIFT) >= sb);
    unsigned take2 = ((int)(v.z >> HSHIFT) >= sb);
    unsigned take3 = ((int)(v.w >> HSHIFT) >= sb);
    int c = (int)(take0 + take1 + take2 + take3);

    __shared__ int blkcnt, blkbase;
    if (tid == 0) blkcnt = 0;
    __syncthreads();
    int pos = 0;
    if (c) pos = atomicAdd(&blkcnt, c);
    __syncthreads();
    if (tid == 0 && blkcnt > 0)
        blkbase = atomicAdd(&ccount[b * CSTRIDE], blkcnt);
    __syncthreads();
    if (c) {
        float* o = cand + (size_t)b * HW + blkbase + pos;
        if (take0) *o++ = __uint_as_float(v.x);
        if (take1) *o++ = __uint_as_float(v.y);
        if (take2) *o++ = __uint_as_float(v.z);
        if (take3) *o = __uint_as_float(v.w);
    }
}

// Exact top-200 mean via radix select over candidates (parallel suffix scans).
__global__ __launch_bounds__(256) void topk_kernel(
    const float* __restrict__ cand, const int* __restrict__ ccount,
    float* __restrict__ score) {
    int b = blockIdx.x;
    const float* s = cand + (size_t)b * HW;
    const unsigned* u = (const unsigned*)s;
    int M = ccount[b * CSTRIDE];
    __shared__ unsigned hist[256];
    __shared__ unsigned ss[257];
    __shared__ unsigned sh_prefix;
    __shared__ int sh_k;
    int tid = threadIdx.x;

    unsigned prefix = 0;
    int k = TOPK;
    for (int dgt = 3; dgt >= 0; --dgt) {
        hist[tid] = 0;
        __syncthreads();
        for (int i = tid; i < M; i += 256) {
            unsigned v = u[i];
            bool match = (dgt == 3) || ((v >> (8 * (dgt + 1))) == prefix);
            if (match) atomicAdd(&hist[(v >> (8 * dgt)) & 255u], 1u);
        }
        __syncthreads();
        ss[tid] = hist[tid];
        if (tid == 0) ss[256] = 0;
        __syncthreads();
#pragma unroll
        for (int st = 1; st < 256; st <<= 1) {
            unsigned add = (tid + st < 256) ? ss[tid + st] : 0u;
            __syncthreads();
            ss[tid] += add;
            __syncthreads();
        }
        if ((int)ss[tid] >= k && (int)ss[tid + 1] < k) {
            sh_prefix = (prefix << 8) | (unsigned)tid;
            sh_k = k - (int)ss[tid + 1];
        }
        __syncthreads();
        prefix = sh_prefix;
        k = sh_k;
        __syncthreads();
    }

    float thr = __uint_as_float(prefix);
    float sum = 0.f;
    int cnt = 0;
    for (int i = tid; i < M; i += 256) {
        float v = s[i];
        if (v > thr) { sum += v; cnt++; }
    }
#pragma unroll
    for (int off = 32; off > 0; off >>= 1) {
        sum += __shfl_xor(sum, off);
        cnt += __shfl_xor(cnt, off);
    }
    __shared__ float wsum[4];
    __shared__ int wcnt[4];
    int wv = tid >> 6;
    if ((tid & 63) == 0) { wsum[wv] = sum; wcnt[wv] = cnt; }
    __syncthreads();
    if (tid == 0) {
        float s2 = 0.f;
        int c2 = 0;
        for (int i = 0; i < 4; ++i) { s2 += wsum[i]; c2 += wcnt[i]; }
        score[b] = (s2 + (float)(TOPK - c2) * thr) * (1.0f / TOPK);
    }
}

extern "C" void kernel_launch(void* const* d_in, const int* in_sizes, int n_in,
                              void* d_out, int out_size, void* d_ws, size_t ws_size,
                              hipStream_t stream) {
    const float* mid = (const float*)d_in[0];
    const float* last = (const float*)d_in[1];
    const float* pmid = (const float*)d_in[2];
    const float* plast = (const float*)d_in[3];
    int B = in_sizes[0] / (NPATCH * C);  // 16

    float* out_map = (float*)d_out;                   // B*448*448
    float* out_score = out_map + (size_t)B * HW;      // B

    // ws layout
    float* combined = (float*)d_ws;                          // 0..64K
    int* meta = (int*)((char*)d_ws + 64 * 1024);             // 64K..80K
    int* ccount = meta;                                      // [b*CSTRIDE]
    int* selbin = meta + 1024;                               // +4KB
    unsigned* hist = (unsigned*)((char*)d_ws + 80 * 1024);   // 80K..592K
    float* Gw = (float*)((char*)d_ws + 592 * 1024);          // 57,344B
    float* Tw = (float*)((char*)d_ws + 652 * 1024);          // 896KB
    float* cand = (float*)((char*)d_ws + 1548 * 1024);       // B*HW floats

    int rows = B * NPATCH;
    int n4 = (528 * 1024) / 16;  // meta (16KB) + hist (512KB)
    anom_kernel<<<(rows + 3) / 4, 256, 0, stream>>>(
        mid, last, pmid, plast, combined,
        (uint4*)((char*)d_ws + 64 * 1024), n4, rows);

    stageA_kernel<<<B, 448, 0, stream>>>(combined, Gw, Tw);
    stageB_kernel<<<B * 16, 448, 0, stream>>>(Tw, Gw, out_map, hist);

    select_kernel<<<B, 256, 0, stream>>>(hist, selbin);
    int nc = (B * HW) / 1024;
    compact_kernel<<<nc, 256, 0, stream>>>(out_map, selbin, ccount, cand);
    topk_kernel<<<B, 256, 0, stream>>>(cand, ccount, out_score);
}